// Round 20
// baseline (243.464 us; speedup 1.0000x reference)
//
#include <hip/hip_runtime.h>
#include <hip/hip_bf16.h>
#include <cstdint>

#define BN_EPS 1e-5f

typedef short bf16x8 __attribute__((ext_vector_type(8)));
typedef _Float16 f16x8 __attribute__((ext_vector_type(8)));
typedef float f32x4 __attribute__((ext_vector_type(4)));

// ---------- helpers ----------
__device__ __forceinline__ float bf16hi_to_f(uint32_t hi) {
    union { uint32_t u; float f; } c; c.u = hi; return c.f;
}
__device__ __forceinline__ uint32_t f_to_bf16(float f) {
    union { float f; uint32_t u; } c; c.f = f;
    uint32_t r = c.u + 0x7fffu + ((c.u >> 16) & 1u);  // RNE
    return r >> 16;
}
__device__ __forceinline__ unsigned short f_to_f16(float f) {
    _Float16 h = (_Float16)f;      // v_cvt_f16_f32, RNE
    union { _Float16 h; unsigned short u; } c; c.h = h; return c.u;
}

// ---------- P1: fused prep: wkF + wqvF + BN affines ----------
__global__ __launch_bounds__(256) void pam_prep1(
    const float* __restrict__ wk, const float* __restrict__ wq, const float* __restrict__ wv,
    const float* __restrict__ bq, const float* __restrict__ qs, const float* __restrict__ qb,
    const float* __restrict__ qm, const float* __restrict__ qv,
    const float* __restrict__ bk, const float* __restrict__ ks, const float* __restrict__ kb,
    const float* __restrict__ km, const float* __restrict__ kv,
    const float* __restrict__ ds, const float* __restrict__ db,
    const float* __restrict__ dm, const float* __restrict__ dv,
    unsigned short* __restrict__ wkF, unsigned short* __restrict__ wqvF,
    float* __restrict__ affQ, float* __restrict__ affK, float* __restrict__ affD) {
    int blk = blockIdx.x, t = threadIdx.x;
    if (blk < 1152) {
        int o = blk * 256 + t;                    // < 9*64*512
        int c = o & 511; int d = (o >> 9) & 63; int tap = o >> 15;
        float v = wk[((size_t)d * 512 + c) * 9 + tap];
        int dt = d >> 4, lm = d & 15, cs = c >> 5, g = (c >> 3) & 3, j = c & 7;
        size_t idx = (((size_t)((tap * 4 + dt) * 16 + cs)) * 64 + g * 16 + lm) * 8 + j;
        wkF[idx] = f_to_f16(v);
    } else if (blk < 1792) {
        int o = (blk - 1152) * 256 + t;           // < 320*512
        int c = o & 511, R = o >> 9;
        float v;
        if (R < 64) {
            float inv = qs[R] * rsqrtf(qv[R] + BN_EPS);
            v = wq[(size_t)R * 512 + c] * inv;
        } else {
            v = wv[(size_t)(R - 64) * 512 + c];
        }
        int ct = R >> 4, lmr = R & 15, cs = c >> 5, g = (c >> 3) & 3, j = c & 7;
        size_t idx = (((size_t)(ct * 16 + cs)) * 64 + g * 16 + lmr) * 8 + j;
        wqvF[idx] = f_to_f16(v);
    } else {
        int i = (blk - 1792) * 256 + t;           // < 640
        if (i < 64) {
            float inv = qs[i] * rsqrtf(qv[i] + BN_EPS);
            affQ[i] = inv; affQ[64 + i] = bq[i] * inv + qb[i] - qm[i] * inv;
        } else if (i < 128) {
            int k = i - 64;
            float inv = ks[k] * rsqrtf(kv[k] + BN_EPS);
            affK[k] = inv; affK[64 + k] = bk[k] * inv + kb[k] - km[k] * inv;
        } else if (i < 640) {
            int k = i - 128;
            float inv = ds[k] * rsqrtf(dv[k] + BN_EPS);
            affD[k] = inv; affD[512 + k] = db[k] - dm[k] * inv;
        }
    }
}

// ---------- P2: fused prep (post-kconv): wdF + zero outsP pads ----------
__global__ __launch_bounds__(256) void pam_prep2(
    const float* __restrict__ wd, unsigned short* __restrict__ wdF,
    unsigned short* __restrict__ p) {
    int blk = blockIdx.x, t = threadIdx.x;
    if (blk < 4608) {
        int o = blk * 256 + t;                    // < 9*512*256
        int ci = o & 255; int co = (o >> 8) & 511; int tap = o >> 17;
        float v = wd[(size_t)ci * 4608 + co * 9 + tap];
        int ct = co >> 4, lmr = co & 15, cs = ci >> 5, g = (ci >> 3) & 3, j = ci & 7;
        size_t idx = (((size_t)(tap * 32 + ct) * 8 + cs) * 512) + g * 128 + lmr * 8 + j;
        wdF[idx] = (unsigned short)f_to_bf16(v);
    } else {
        size_t i = ((size_t)(blk - 4608) * 256 + t) * 8;   // total 2,230,272 ushorts
        uint4 z = make_uint4(0, 0, 0, 0);
        *(uint4*)(p + i) = z;
    }
}

// ---------- K1c: x -> xF[b][65][65][512] f16, LDS-transposed (full-line writes) ----------
__global__ __launch_bounds__(256) void pam_xt(const float* __restrict__ x,
                                              unsigned short* __restrict__ xF) {
    __shared__ unsigned short lds[2][32][72];
    int t = threadIdx.x;
    int ri = blockIdx.x;       // 0..64 ; input row hi = ri-1
    int b = blockIdx.y;
    size_t rowbase = ((size_t)b * 65 + ri) * 65 * 512;
    uint4 z = make_uint4(0, 0, 0, 0);
    if (ri == 0) {
        for (int idx = t; idx < 65 * 512 / 8; idx += 256)
            *(uint4*)(xF + rowbase + (size_t)idx * 8) = z;
        return;
    }
    if (t < 64)
        *(uint4*)(xF + rowbase + (size_t)t * 8) = z;   // wi = -1 guard col
    int hi = ri - 1;
    int wi = t & 63, cl = t >> 6;          // reader mapping (lanes over wi: coalesced)
    int px = t >> 2, c4 = (t & 3) * 8;     // writer mapping (4 lanes = one 64B line)
    const float* xb = x + (size_t)b * 512 * 4096 + (size_t)hi * 64 + wi;
    for (int ch = 0; ch < 16; ++ch) {
        unsigned short v[8];
        #pragma unroll
        for (int j = 0; j < 8; j++)
            v[j] = f_to_f16(xb[(size_t)(ch * 32 + cl * 8 + j) * 4096]);
        #pragma unroll
        for (int j = 0; j < 8; j++)
            lds[ch & 1][cl * 8 + j][wi] = v[j];
        __syncthreads();
        unsigned short w[8];
        #pragma unroll
        for (int j = 0; j < 8; j++)
            w[j] = lds[ch & 1][c4 + j][px];
        uint4 pw = make_uint4((uint32_t)w[0] | ((uint32_t)w[1] << 16),
                              (uint32_t)w[2] | ((uint32_t)w[3] << 16),
                              (uint32_t)w[4] | ((uint32_t)w[5] << 16),
                              (uint32_t)w[6] | ((uint32_t)w[7] << 16));
        *(uint4*)(xF + rowbase + (size_t)(px + 1) * 512 + ch * 32 + c4) = pw;
    }
}

// ---------- K2: fused q+v 1x1 conv as f16 MFMA GEMM; q stored f16, v bf16 ----------
__global__ __launch_bounds__(256, 4) void pam_qv_mfma(
    const unsigned short* __restrict__ xF,
    const unsigned short* __restrict__ wqvF,
    const float* __restrict__ affQ, const float* __restrict__ bv,
    unsigned short* __restrict__ qF,
    unsigned short* __restrict__ vF) {
    int t = threadIdx.x;
    int hb = blockIdx.x, b = blockIdx.y;
    int h = hb >> 1, phf = hb & 1;
    int wv_ = t >> 6, lane = t & 63, g = lane >> 4, lm = lane & 15;
    int ct0 = wv_ * 5;

    f32x4 acc[5][2];
    #pragma unroll
    for (int m = 0; m < 5; m++)
        #pragma unroll
        for (int n = 0; n < 2; n++) acc[m][n] = (f32x4){0.f, 0.f, 0.f, 0.f};

    const unsigned short* xb = xF + (((size_t)(b * 65) + h + 1) * 65 + 1) * 512
                               + (size_t)(phf * 32 + lm) * 512 + g * 8;
    const unsigned short* wb = wqvF + (size_t)lane * 8;

    #pragma unroll 4
    for (int cs = 0; cs < 16; cs++) {
        int coff = cs * 32;
        f16x8 bfr[2];
        #pragma unroll
        for (int nt = 0; nt < 2; nt++)
            bfr[nt] = *(const f16x8*)(xb + (size_t)nt * 16 * 512 + coff);
        f16x8 afr[5];
        #pragma unroll
        for (int m = 0; m < 5; m++)
            afr[m] = *(const f16x8*)(wb + (size_t)((ct0 + m) * 16 + cs) * 512);
        #pragma unroll
        for (int m = 0; m < 5; m++)
            #pragma unroll
            for (int n = 0; n < 2; n++)
                acc[m][n] = __builtin_amdgcn_mfma_f32_16x16x32_f16(afr[m], bfr[n], acc[m][n], 0, 0, 0);
    }

    #pragma unroll
    for (int m = 0; m < 5; m++) {
        #pragma unroll
        for (int i = 0; i < 4; i++) {
            int R = (ct0 + m) * 16 + g * 4 + i;
            float shift = (R < 64) ? affQ[64 + R] : bv[R - 64];
            if (R < 64) {
                int s_ = R >> 5, gF = (R >> 3) & 3, jF = R & 7;
                #pragma unroll
                for (int nt = 0; nt < 2; nt++) {
                    int p = h * 64 + phf * 32 + nt * 16 + lm;
                    float val = acc[m][nt][i] + shift;
                    size_t idx = (size_t)(b * 256 + (p >> 4)) * 1024 + s_ * 512 + gF * 128 + (p & 15) * 8 + jF;
                    qF[idx] = f_to_f16(val);
                }
            } else {
                int c = R - 64;
                #pragma unroll
                for (int nt = 0; nt < 2; nt++) {
                    int p = h * 64 + phf * 32 + nt * 16 + lm;
                    float val = acc[m][nt][i] + shift;
                    size_t idx = (size_t)(b * 128 + (p >> 5)) * 8192 + (c >> 4) * 512 +
                                 ((p >> 3) & 3) * 128 + (c & 15) * 8 + (p & 7);
                    vF[idx] = (unsigned short)f_to_bf16(val);
                }
            }
        }
    }
}

// ---------- K3: k-conv as tap-decomposed f16 MFMA GEMM, 16 waves, 4-way c-split ----------
__global__ __launch_bounds__(1024, 4) void pam_kconv_mfma(
    const unsigned short* __restrict__ xF,
    const unsigned short* __restrict__ wkF,
    const float* __restrict__ affK,
    unsigned short* __restrict__ kF) {
    __shared__ float red[3 * 4 * 64 * 8];   // 24 KiB
    int t = threadIdx.x;
    int hk = blockIdx.x, b = blockIdx.y;
    int wid = t >> 6, lane = t & 63, g = lane >> 4, lm = lane & 15;
    int dt = wid & 3, cq = wid >> 2;
    int goff = g * 8;
    f32x4 acc0 = (f32x4){0.f, 0.f, 0.f, 0.f};
    f32x4 acc1 = (f32x4){0.f, 0.f, 0.f, 0.f};
    #pragma unroll
    for (int r = 0; r < 3; r++) {
        size_t arow = ((size_t)(b * 65 + 2 * hk + r)) * 65 * 512;
        #pragma unroll
        for (int s = 0; s < 3; s++) {
            size_t aoff = arow + (size_t)(2 * lm + s) * 512 + goff;   // pixel wk=lm
            const unsigned short* pa0 = xF + aoff;
            int tap = r * 3 + s;
            const unsigned short* pb = wkF + (((size_t)(tap * 4 + dt) * 16) * 64 + lane) * 8;
            #pragma unroll
            for (int k = 0; k < 4; k++) {
                int c0 = cq * 128 + k * 32;
                f16x8 a0 = *(const f16x8*)(pa0 + c0);
                f16x8 a1 = *(const f16x8*)(pa0 + 32 * 512 + c0);   // pixel wk=lm+16
                f16x8 bf = *(const f16x8*)(pb + (size_t)(c0 >> 5) * 512);
                acc0 = __builtin_amdgcn_mfma_f32_16x16x32_f16(a0, bf, acc0, 0, 0, 0);
                acc1 = __builtin_amdgcn_mfma_f32_16x16x32_f16(a1, bf, acc1, 0, 0, 0);
            }
        }
    }
    if (cq > 0) {
        float* dst = red + (((size_t)(cq - 1) * 4 + dt) * 64 + lane) * 8;
        *(f32x4*)dst = acc0;
        *(f32x4*)(dst + 4) = acc1;
    }
    __syncthreads();
    if (cq != 0) return;
    #pragma unroll
    for (int q = 0; q < 3; q++) {
        const float* src = red + (((size_t)q * 4 + dt) * 64 + lane) * 8;
        f32x4 p0 = *(const f32x4*)src;
        f32x4 p1 = *(const f32x4*)(src + 4);
        acc0 += p0; acc1 += p1;
    }
    int d = dt * 16 + lm;
    float sc = affK[d], sh = affK[64 + d];
    int s_ = d >> 5, gF = (d >> 3) & 3, jF = d & 7;
    #pragma unroll
    for (int i = 0; i < 4; i++) {
        int m1 = hk * 32 + g * 4 + i;         // acc0 pixel
        int m2 = m1 + 16;                     // acc1 pixel
        float v0 = fmaf(acc0[i], sc, sh);
        float v1 = fmaf(acc1[i], sc, sh);
        size_t i1 = (size_t)(b * 64 + (m1 >> 4)) * 1024 + s_ * 512 + gF * 128 + (m1 & 15) * 8 + jF;
        kF[i1] = f_to_f16(v0);
        size_t i2 = (size_t)(b * 64 + (m2 >> 4)) * 1024 + s_ * 512 + gF * 128 + (m2 & 15) * 8 + jF;
        kF[i2] = f_to_f16(v1);
    }
}

// ---------- K4: flash attention, 32 m-rows/block, 8 n-phases, 512 thr (2 blocks/CU) ----------
// wave: (mtl = wid&1 m-tile, wp = wid>>1 n-slice of 128). P LDS 32KB [ks 16][gF 4][m 32][j 8].
// PV: wave -> 32 c (2 c-tiles) x both m-tiles. V traffic per block: full V per 32 rows (halved).
__global__ __launch_bounds__(512, 4) void pam_attn(
    const unsigned short* __restrict__ qF,
    const unsigned short* __restrict__ kF,
    const unsigned short* __restrict__ vF, unsigned short* __restrict__ outsP) {
    __shared__ unsigned short Pl[16384];   // 32 KiB
    __shared__ float redM[2][4][16];
    __shared__ float redS[2][4][16];
    int t = threadIdx.x;
    int b = blockIdx.x, mt2 = blockIdx.y;
    int wid = t >> 6, lane = t & 63;
    int g = lane >> 4, lm = lane & 15;
    int mtl = wid & 1, wp = wid >> 1;

    size_t kidx = (size_t)(b * 64 + mt2 * 2 + mtl) * 1024 + g * 128 + lm * 8;
    f16x8 kf0 = *(const f16x8*)(kF + kidx);
    f16x8 kf1 = *(const f16x8*)(kF + kidx + 512);

    float Mrun[2][4], rsum[4];
    #pragma unroll
    for (int i = 0; i < 4; i++) { Mrun[0][i] = -3e38f; Mrun[1][i] = -3e38f; rsum[i] = 0.f; }
    // o accumulators: [m-tile][c-tile A/B]
    f32x4 o0A = (f32x4){0.f,0.f,0.f,0.f}, o0B = o0A, o1A = o0A, o1B = o0A;

    const unsigned short* qhb = qF + (size_t)(b * 256) * 1024 + g * 128 + lm * 8;
    const unsigned short* vb  = vF + (size_t)b * 1048576 + (wid * 2) * 512 + g * 128 + lm * 8;

    for (int ph = 0; ph < 8; ++ph) {
        // --- energy: 8 ftiles (n = ph*512 + wp*128 + [0,128)) ---
        f32x4 ev[8];
        #pragma unroll
        for (int f = 0; f < 8; f++) ev[f] = (f32x4){0.f, 0.f, 0.f, 0.f};
        int ft0 = ph * 32 + wp * 8;
        #pragma unroll
        for (int f = 0; f < 8; f++) {
            const unsigned short* qhp = qhb + (size_t)(ft0 + f) * 1024;
            f16x8 qf0 = *(const f16x8*)(qhp);
            f16x8 qf1 = *(const f16x8*)(qhp + 512);
            f32x4 e = ev[f];
            e = __builtin_amdgcn_mfma_f32_16x16x32_f16(kf0, qf0, e, 0, 0, 0);
            e = __builtin_amdgcn_mfma_f32_16x16x32_f16(kf1, qf1, e, 0, 0, 0);
            ev[f] = e;
        }
        // --- per-wave local max (own m-tile rows) ---
        float pm[4];
        #pragma unroll
        for (int i = 0; i < 4; i++) {
            float m_ = ev[0][i];
            #pragma unroll
            for (int f = 1; f < 8; f++) m_ = fmaxf(m_, ev[f][i]);
            #pragma unroll
            for (int off = 1; off < 16; off <<= 1) m_ = fmaxf(m_, __shfl_xor(m_, off));
            pm[i] = m_;
        }
        // redM write without pre-barrier: prev phase's P-ready barrier separates it
        // from that phase's redM readers; PV never touches redM.
        if (lm == 0) {
            #pragma unroll
            for (int i = 0; i < 4; i++) redM[mtl][wp][g * 4 + i] = pm[i];
        }
        __syncthreads();   // redM visible; prev-phase PV reads of Pl complete
        // --- running max update + rescale (both m-tiles) ---
        float rfac[2][4];
        #pragma unroll
        for (int mt = 0; mt < 2; mt++) {
            #pragma unroll
            for (int i = 0; i < 4; i++) {
                float pmax = redM[mt][0][g * 4 + i];
                #pragma unroll
                for (int w2 = 1; w2 < 4; w2++) pmax = fmaxf(pmax, redM[mt][w2][g * 4 + i]);
                float Mn = fmaxf(Mrun[mt][i], pmax);
                rfac[mt][i] = __expf(Mrun[mt][i] - Mn);
                Mrun[mt][i] = Mn;
            }
        }
        #pragma unroll
        for (int i = 0; i < 4; i++) {
            rsum[i] *= rfac[mtl][i];
            o0A[i] *= rfac[0][i]; o0B[i] *= rfac[0][i];
            o1A[i] *= rfac[1][i]; o1B[i] *= rfac[1][i];
        }
        // --- exp, bf16 round, sum of ROUNDED values, store P frag-linear ---
        #pragma unroll
        for (int f = 0; f < 8; f++) {
            int ntl = wp * 8 + f;            // local ntile 0..31
            int ks = ntl >> 1;               // 0..15
            int gF = (ntl & 1) * 2 + (lm >> 3);
            int jF = lm & 7;
            #pragma unroll
            for (int i = 0; i < 4; i++) {
                float p = __expf(ev[f][i] - Mrun[mtl][i]);
                uint32_t u = f_to_bf16(p);
                rsum[i] += bf16hi_to_f(u << 16);
                Pl[((ks * 4 + gF) * 32 + mtl * 16 + g * 4 + i) * 8 + jF] = (unsigned short)u;
            }
        }
        __syncthreads();   // P ready
        // --- PV: 2 c-tiles (c = wid*32 + {lm,16+lm}) x both m-tiles, 16 ks ---
        #pragma unroll 4
        for (int ks = 0; ks < 16; ks++) {
            bf16x8 pa0 = *(const bf16x8*)(Pl + ((ks * 4 + g) * 32 + lm) * 8);
            bf16x8 pa1 = *(const bf16x8*)(Pl + ((ks * 4 + g) * 32 + 16 + lm) * 8);
            bf16x8 bvA = *(const bf16x8*)(vb + (size_t)(ph * 16 + ks) * 8192);
            bf16x8 bvB = *(const bf16x8*)(vb + (size_t)(ph * 16 + ks) * 8192 + 512);
            o0A = __builtin_amdgcn_mfma_f32_16x16x32_bf16(pa0, bvA, o0A, 0, 0, 0);
            o0B = __builtin_amdgcn_mfma_f32_16x16x32_bf16(pa0, bvB, o0B, 0, 0, 0);
            o1A = __builtin_amdgcn_mfma_f32_16x16x32_bf16(pa1, bvA, o1A, 0, 0, 0);
            o1B = __builtin_amdgcn_mfma_f32_16x16x32_bf16(pa1, bvB, o1B, 0, 0, 0);
        }
    }

    // --- final sum reduction + normalize + write ---
    #pragma unroll
    for (int i = 0; i < 4; i++) {
        float s_ = rsum[i];
        #pragma unroll
        for (int off = 1; off < 16; off <<= 1) s_ += __shfl_xor(s_, off);
        rsum[i] = s_;
    }
    __syncthreads();
    if (lm == 0) {
        #pragma unroll
        for (int i = 0; i < 4; i++) redS[mtl][wp][g * 4 + i] = rsum[i];
    }
    __syncthreads();
    int c0 = wid * 32;
    #pragma unroll
    for (int mt = 0; mt < 2; mt++) {
        #pragma unroll
        for (int i = 0; i < 4; i++) {
            float s_ = 0.f;
            #pragma unroll
            for (int w2 = 0; w2 < 4; w2++) s_ += redS[mt][w2][g * 4 + i];
            float sinv = 1.f / s_;
            int m = mt2 * 32 + mt * 16 + g * 4 + i;
            int hk2 = m >> 5, wk2 = m & 31;
            unsigned short* op = outsP + (((size_t)(b * 33 + hk2)) * 33 + wk2) * 256;
            float vA = (mt == 0) ? o0A[i] : o1A[i];
            float vB = (mt == 0) ? o0B[i] : o1B[i];
            op[c0 + lm]      = (unsigned short)f_to_bf16(vA * sinv);
            op[c0 + 16 + lm] = (unsigned short)f_to_bf16(vB * sinv);
        }
    }
}

// ---------- K5: transpose-conv as balanced row-pair MFMA, 2-block co-split ----------
template<int LROW, int KH, int KW>
__device__ __forceinline__ void deconv_tap(
    const unsigned short* __restrict__ wdF,
    const char* lb, int ct0, int lane, int lm, f32x4 (&acc)[2][2][2]) {
    constexpr int wop = (KW == 1) ? 0 : 1;
    constexpr int dw = (KW == 0) ? 1 : 0;
    constexpr int tap = KH * 3 + KW;
    int g = lane >> 4;
    int p0 = LROW * 33 + lm + dw;
    int p1 = p0 + 16;
    uint32_t s0 = ((uint32_t)(p0 & 7)) << 4;
    uint32_t s1 = ((uint32_t)(p1 & 7)) << 4;
    uint32_t b0a = (uint32_t)p0 * 512 + (uint32_t)g * 16;
    uint32_t b1a = (uint32_t)p1 * 512 + (uint32_t)g * 16;
    const unsigned short* a0p = wdF + ((size_t)(tap * 32 + ct0) * 8) * 512 + lane * 8;
    const unsigned short* a1p = a0p + 8 * 512;     // ct0+1
    #pragma unroll
    for (int cs = 0; cs < 8; cs++) {
        bf16x8 bv0 = *(const bf16x8*)(lb + ((b0a + (uint32_t)cs * 64) ^ s0));
        bf16x8 bv1 = *(const bf16x8*)(lb + ((b1a + (uint32_t)cs * 64) ^ s1));
        bf16x8 a0 = *(const bf16x8*)(a0p + cs * 512);
        bf16x8 a1 = *(const bf16x8*)(a1p + cs * 512);
        acc[wop][0][0] = __builtin_amdgcn_mfma_f32_16x16x32_bf16(a0, bv0, acc[wop][0][0], 0, 0, 0);
        acc[wop][0][1] = __builtin_amdgcn_mfma_f32_16x16x32_bf16(a0, bv1, acc[wop][0][1], 0, 0, 0);
        acc[wop][1][0] = __builtin_amdgcn_mfma_f32_16x16x32_bf16(a1, bv0, acc[wop][1][0], 0, 0, 0);
        acc[wop][1][1] = __builtin_amdgcn_mfma_f32_16x16x32_bf16(a1, bv1, acc[wop][1][1], 0, 0, 0);
    }
}

__device__ __forceinline__ void deconv_epi(
    const f32x4 (&acc)[2][2][2], const float* __restrict__ affD,
    const float* __restrict__ x, float* __restrict__ out,
    int b, int ho, int co0, int lm, int g) {
    #pragma unroll
    for (int mf = 0; mf < 2; mf++) {
        #pragma unroll
        for (int i = 0; i < 4; i++) {
            int co = co0 + mf * 16 + g * 4 + i;
            float sc = affD[co], sh = affD[512 + co];
            const float* xr = x + (((size_t)b * 512 + co) * 64 + ho) * 64;
            float* orow = out + (((size_t)b * 512 + co) * 64 + ho) * 64;
            #pragma unroll
            for (int nf = 0; nf < 2; nf++) {
                int wp = nf * 16 + lm;
                float2 xv = *(const float2*)(xr + 2 * wp);
                float2 st;
                st.x = fmaxf(fmaf(acc[0][mf][nf][i], sc, sh), 0.f) + xv.x;
                st.y = fmaxf(fmaf(acc[1][mf][nf][i], sc, sh), 0.f) + xv.y;
                *(float2*)(orow + 2 * wp) = st;
            }
        }
    }
}

__global__ __launch_bounds__(512, 4) void pam_deconv_mfma(
    const unsigned short* __restrict__ outsP,
    const unsigned short* __restrict__ wdF,
    const float* __restrict__ affD, const float* __restrict__ x, float* __restrict__ out) {
    __shared__ unsigned short Pb[16896];   // 2 rows x 33 px x 256 ci
    int t = threadIdx.x;
    int h0 = blockIdx.x, b = blockIdx.y, zh = blockIdx.z;   // zh = co half
    const unsigned short* src = outsP + ((size_t)(b * 33 + h0) * 33) * 256;
    for (int idx = t; idx < 2112; idx += 512) {
        uint4 v = *(const uint4*)(src + (size_t)idx * 8);
        uint32_t byte = (uint32_t)idx * 16;
        byte ^= ((byte >> 9) & 7) << 4;
        *(uint4*)((char*)Pb + byte) = v;
    }
    __syncthreads();

    int wid = t >> 6, lane = t & 63, g = lane >> 4, lm = lane & 15;
    int ct0 = (zh * 8 + wid) * 2, co0 = (zh * 8 + wid) * 32;
    const char* lb = (const char*)Pb;

    {   // even output row ho = 2*h0 : kh=1, B row h0 (LDS row 0)
        f32x4 acc[2][2][2];
        #pragma unroll
        for (int a = 0; a < 2; a++)
            #pragma unroll
            for (int m = 0; m < 2; m++)
                #pragma unroll
                for (int n = 0; n < 2; n++) acc[a][m][n] = (f32x4){0.f, 0.f, 0.f, 0.f};
        deconv_tap<0, 1, 0>(wdF, lb, ct0, lane, lm, acc);
        deconv_tap<0, 1, 1>(wdF, lb, ct0, lane, lm, acc);
        deconv_tap<0, 1, 2>(wdF, lb, ct0, lane, lm, acc);
        deconv_epi(acc, affD, x, out, b, 2 * h0, co0, lm, g);
    }
    {   // odd output row ho = 2*h0+1 : kh=2 B row h0, kh=0 B row h0+1
        f32x4 acc[2][2][2];
        #pragma unroll
        for (int a = 0; a < 2; a++)
            #pragma unroll
            for (int m = 0; m < 2; m++)
                #pragma unroll
                for (int n = 0; n < 2; n++) acc[a][m][n] = (f32x4){0.f, 0.f, 0.f, 0.f};
        deconv_tap<0, 2, 0>(wdF, lb, ct0, lane, lm, acc);
        deconv_tap<0, 2, 1>(wdF, lb, ct0, lane, lm, acc);
        deconv_tap<0, 2, 2>(wdF, lb, ct0, lane, lm, acc);
        deconv_tap<1, 0, 0>(wdF, lb, ct0, lane, lm, acc);
        deconv_tap<1, 0, 1>(wdF, lb, ct0, lane, lm, acc);
        deconv_tap<1, 0, 2>(wdF, lb, ct0, lane, lm, acc);
        deconv_epi(acc, affD, x, out, b, 2 * h0 + 1, co0, lm, g);
    }
}

// ---------- launcher ----------
extern "C" void kernel_launch(void* const* d_in, const int* in_sizes, int n_in,
                              void* d_out, int out_size, void* d_ws, size_t ws_size,
                              hipStream_t stream) {
    const float* x   = (const float*)d_in[0];
    const float* w_q = (const float*)d_in[1];
    const float* b_q = (const float*)d_in[2];
    const float* qs  = (const float*)d_in[3];
    const float* qb  = (const float*)d_in[4];
    const float* qm  = (const float*)d_in[5];
    const float* qv  = (const float*)d_in[6];
    const float* w_k = (const float*)d_in[7];
    const float* b_k = (const float*)d_in[8];
    const float* ks  = (const float*)d_in[9];
    const float* kb  = (const float*)d_in[10];
    const float* km  = (const float*)d_in[11];
    const float* kv  = (const float*)d_in[12];
    const float* w_v = (const float*)d_in[13];
    const float* b_v = (const float*)d_in[14];
    const float* w_d = (const float*)d_in[15];
    const float* ds  = (const float*)d_in[16];
    const float* db  = (const float*)d_in[17];
    const float* dm  = (const float*)d_in[18];
    const float* dv  = (const float*)d_in[19];
    float* out = (float*)d_out;

    char* wsb = (char*)d_ws;
    unsigned short* qF    = (unsigned short*)(wsb);               //  4,194,304 (f16)
    unsigned short* vF    = (unsigned short*)(wsb + 8388608);     // 16,777,216
    unsigned short* kF    = (unsigned short*)(wsb + 25165824);    //  1,048,576 (f16)
    unsigned short* wqvF  = (unsigned short*)(wsb + 26214400);    //    327,680 (f16)
    unsigned short* wkF   = (unsigned short*)(wsb + 27262976);    //    589,824 (f16)
    float*          affQ  = (float*)(wsb + 28442624);             //        512
    float*          affK  = (float*)(wsb + 28443136);             //        512
    float*          affD  = (float*)(wsb + 28443648);             //      4,096
    // X region: xF f16 live [pam_xt .. pam_kconv_mfma]; then reused:
    unsigned short* xF    = (unsigned short*)(wsb + 28447744);    // 34,611,200
    unsigned short* outsP = (unsigned short*)(wsb + 28447744);    //  4,460,544 (alias)
    unsigned short* wdF   = (unsigned short*)(wsb + 32908288);    //  2,359,296 (alias)

    hipLaunchKernelGGL(pam_prep1, dim3(1795), dim3(256), 0, stream,
                       w_k, w_q, w_v, b_q, qs, qb, qm, qv, b_k, ks, kb, km, kv,
                       ds, db, dm, dv, wkF, wqvF, affQ, affK, affD);
    hipLaunchKernelGGL(pam_xt, dim3(65, 8), dim3(256), 0, stream, x, xF);
    hipLaunchKernelGGL(pam_qv_mfma, dim3(128, 8), dim3(256), 0, stream,
                       xF, wqvF, affQ, b_v, qF, vF);
    hipLaunchKernelGGL(pam_kconv_mfma, dim3(32, 8), dim3(1024), 0, stream,
                       xF, wkF, affK, kF);
    // xF dead from here; aliased region reused for outsP / wdF.
    hipLaunchKernelGGL(pam_prep2, dim3(5697), dim3(256), 0, stream, w_d, wdF, outsP);
    hipLaunchKernelGGL(pam_attn, dim3(8, 32), dim3(512), 0, stream,
                       qF, kF, vF, outsP);
    hipLaunchKernelGGL(pam_deconv_mfma, dim3(32, 8, 2), dim3(512), 0, stream,
                       outsP, wdF, affD, x, out);
}

// Round 21
// 224.027 us; speedup vs baseline: 1.0868x; 1.0868x over previous
//
#include <hip/hip_runtime.h>
#include <hip/hip_bf16.h>
#include <cstdint>

#define BN_EPS 1e-5f

typedef short bf16x8 __attribute__((ext_vector_type(8)));
typedef _Float16 f16x8 __attribute__((ext_vector_type(8)));
typedef float f32x4 __attribute__((ext_vector_type(4)));

// ---------- helpers ----------
__device__ __forceinline__ float bf16hi_to_f(uint32_t hi) {
    union { uint32_t u; float f; } c; c.u = hi; return c.f;
}
__device__ __forceinline__ uint32_t f_to_bf16(float f) {
    union { float f; uint32_t u; } c; c.f = f;
    uint32_t r = c.u + 0x7fffu + ((c.u >> 16) & 1u);  // RNE
    return r >> 16;
}
__device__ __forceinline__ unsigned short f_to_f16(float f) {
    _Float16 h = (_Float16)f;      // v_cvt_f16_f32, RNE
    union { _Float16 h; unsigned short u; } c; c.h = h; return c.u;
}

// ---------- P1: fused prep: wkF + wqvF + BN affines ----------
__global__ __launch_bounds__(256) void pam_prep1(
    const float* __restrict__ wk, const float* __restrict__ wq, const float* __restrict__ wv,
    const float* __restrict__ bq, const float* __restrict__ qs, const float* __restrict__ qb,
    const float* __restrict__ qm, const float* __restrict__ qv,
    const float* __restrict__ bk, const float* __restrict__ ks, const float* __restrict__ kb,
    const float* __restrict__ km, const float* __restrict__ kv,
    const float* __restrict__ ds, const float* __restrict__ db,
    const float* __restrict__ dm, const float* __restrict__ dv,
    unsigned short* __restrict__ wkF, unsigned short* __restrict__ wqvF,
    float* __restrict__ affQ, float* __restrict__ affK, float* __restrict__ affD) {
    int blk = blockIdx.x, t = threadIdx.x;
    if (blk < 1152) {
        int o = blk * 256 + t;                    // < 9*64*512
        int c = o & 511; int d = (o >> 9) & 63; int tap = o >> 15;
        float v = wk[((size_t)d * 512 + c) * 9 + tap];
        int dt = d >> 4, lm = d & 15, cs = c >> 5, g = (c >> 3) & 3, j = c & 7;
        size_t idx = (((size_t)((tap * 4 + dt) * 16 + cs)) * 64 + g * 16 + lm) * 8 + j;
        wkF[idx] = f_to_f16(v);
    } else if (blk < 1792) {
        int o = (blk - 1152) * 256 + t;           // < 320*512
        int c = o & 511, R = o >> 9;
        float v;
        if (R < 64) {
            float inv = qs[R] * rsqrtf(qv[R] + BN_EPS);
            v = wq[(size_t)R * 512 + c] * inv;
        } else {
            v = wv[(size_t)(R - 64) * 512 + c];
        }
        int ct = R >> 4, lmr = R & 15, cs = c >> 5, g = (c >> 3) & 3, j = c & 7;
        size_t idx = (((size_t)(ct * 16 + cs)) * 64 + g * 16 + lmr) * 8 + j;
        wqvF[idx] = f_to_f16(v);
    } else {
        int i = (blk - 1792) * 256 + t;           // < 640
        if (i < 64) {
            float inv = qs[i] * rsqrtf(qv[i] + BN_EPS);
            affQ[i] = inv; affQ[64 + i] = bq[i] * inv + qb[i] - qm[i] * inv;
        } else if (i < 128) {
            int k = i - 64;
            float inv = ks[k] * rsqrtf(kv[k] + BN_EPS);
            affK[k] = inv; affK[64 + k] = bk[k] * inv + kb[k] - km[k] * inv;
        } else if (i < 640) {
            int k = i - 128;
            float inv = ds[k] * rsqrtf(dv[k] + BN_EPS);
            affD[k] = inv; affD[512 + k] = db[k] - dm[k] * inv;
        }
    }
}

// ---------- P2: fused prep (post-kconv): wdF + zero outsP pads ----------
__global__ __launch_bounds__(256) void pam_prep2(
    const float* __restrict__ wd, unsigned short* __restrict__ wdF,
    unsigned short* __restrict__ p) {
    int blk = blockIdx.x, t = threadIdx.x;
    if (blk < 4608) {
        int o = blk * 256 + t;                    // < 9*512*256
        int ci = o & 255; int co = (o >> 8) & 511; int tap = o >> 17;
        float v = wd[(size_t)ci * 4608 + co * 9 + tap];
        int ct = co >> 4, lmr = co & 15, cs = ci >> 5, g = (ci >> 3) & 3, j = ci & 7;
        size_t idx = (((size_t)(tap * 32 + ct) * 8 + cs) * 512) + g * 128 + lmr * 8 + j;
        wdF[idx] = (unsigned short)f_to_bf16(v);
    } else {
        size_t i = ((size_t)(blk - 4608) * 256 + t) * 8;   // total 2,230,272 ushorts
        uint4 z = make_uint4(0, 0, 0, 0);
        *(uint4*)(p + i) = z;
    }
}

// ---------- K1c: x -> xF[b][65][65][512] f16, LDS-transposed (full-line writes) ----------
__global__ __launch_bounds__(256) void pam_xt(const float* __restrict__ x,
                                              unsigned short* __restrict__ xF) {
    __shared__ unsigned short lds[2][32][72];
    int t = threadIdx.x;
    int ri = blockIdx.x;       // 0..64 ; input row hi = ri-1
    int b = blockIdx.y;
    size_t rowbase = ((size_t)b * 65 + ri) * 65 * 512;
    uint4 z = make_uint4(0, 0, 0, 0);
    if (ri == 0) {
        for (int idx = t; idx < 65 * 512 / 8; idx += 256)
            *(uint4*)(xF + rowbase + (size_t)idx * 8) = z;
        return;
    }
    if (t < 64)
        *(uint4*)(xF + rowbase + (size_t)t * 8) = z;   // wi = -1 guard col
    int hi = ri - 1;
    int wi = t & 63, cl = t >> 6;          // reader mapping (lanes over wi: coalesced)
    int px = t >> 2, c4 = (t & 3) * 8;     // writer mapping (4 lanes = one 64B line)
    const float* xb = x + (size_t)b * 512 * 4096 + (size_t)hi * 64 + wi;
    for (int ch = 0; ch < 16; ++ch) {
        unsigned short v[8];
        #pragma unroll
        for (int j = 0; j < 8; j++)
            v[j] = f_to_f16(xb[(size_t)(ch * 32 + cl * 8 + j) * 4096]);
        #pragma unroll
        for (int j = 0; j < 8; j++)
            lds[ch & 1][cl * 8 + j][wi] = v[j];
        __syncthreads();
        unsigned short w[8];
        #pragma unroll
        for (int j = 0; j < 8; j++)
            w[j] = lds[ch & 1][c4 + j][px];
        uint4 pw = make_uint4((uint32_t)w[0] | ((uint32_t)w[1] << 16),
                              (uint32_t)w[2] | ((uint32_t)w[3] << 16),
                              (uint32_t)w[4] | ((uint32_t)w[5] << 16),
                              (uint32_t)w[6] | ((uint32_t)w[7] << 16));
        *(uint4*)(xF + rowbase + (size_t)(px + 1) * 512 + ch * 32 + c4) = pw;
    }
}

// ---------- K2: fused q+v 1x1 conv as f16 MFMA GEMM; q stored f16, v bf16 ----------
// grid (128, 8): blockIdx.x = h*2 + pixel-half -> 1024 blocks = 4/CU.
__global__ __launch_bounds__(256, 4) void pam_qv_mfma(
    const unsigned short* __restrict__ xF,
    const unsigned short* __restrict__ wqvF,
    const float* __restrict__ affQ, const float* __restrict__ bv,
    unsigned short* __restrict__ qF,
    unsigned short* __restrict__ vF) {
    int t = threadIdx.x;
    int hb = blockIdx.x, b = blockIdx.y;
    int h = hb >> 1, phf = hb & 1;
    int wv_ = t >> 6, lane = t & 63, g = lane >> 4, lm = lane & 15;
    int ct0 = wv_ * 5;

    f32x4 acc[5][2];
    #pragma unroll
    for (int m = 0; m < 5; m++)
        #pragma unroll
        for (int n = 0; n < 2; n++) acc[m][n] = (f32x4){0.f, 0.f, 0.f, 0.f};

    const unsigned short* xb = xF + (((size_t)(b * 65) + h + 1) * 65 + 1) * 512
                               + (size_t)(phf * 32 + lm) * 512 + g * 8;
    const unsigned short* wb = wqvF + (size_t)lane * 8;

    #pragma unroll 4
    for (int cs = 0; cs < 16; cs++) {
        int coff = cs * 32;
        f16x8 bfr[2];
        #pragma unroll
        for (int nt = 0; nt < 2; nt++)
            bfr[nt] = *(const f16x8*)(xb + (size_t)nt * 16 * 512 + coff);
        f16x8 afr[5];
        #pragma unroll
        for (int m = 0; m < 5; m++)
            afr[m] = *(const f16x8*)(wb + (size_t)((ct0 + m) * 16 + cs) * 512);
        #pragma unroll
        for (int m = 0; m < 5; m++)
            #pragma unroll
            for (int n = 0; n < 2; n++)
                acc[m][n] = __builtin_amdgcn_mfma_f32_16x16x32_f16(afr[m], bfr[n], acc[m][n], 0, 0, 0);
    }

    #pragma unroll
    for (int m = 0; m < 5; m++) {
        #pragma unroll
        for (int i = 0; i < 4; i++) {
            int R = (ct0 + m) * 16 + g * 4 + i;
            float shift = (R < 64) ? affQ[64 + R] : bv[R - 64];
            if (R < 64) {
                int s_ = R >> 5, gF = (R >> 3) & 3, jF = R & 7;
                #pragma unroll
                for (int nt = 0; nt < 2; nt++) {
                    int p = h * 64 + phf * 32 + nt * 16 + lm;
                    float val = acc[m][nt][i] + shift;
                    size_t idx = (size_t)(b * 256 + (p >> 4)) * 1024 + s_ * 512 + gF * 128 + (p & 15) * 8 + jF;
                    qF[idx] = f_to_f16(val);
                }
            } else {
                int c = R - 64;
                #pragma unroll
                for (int nt = 0; nt < 2; nt++) {
                    int p = h * 64 + phf * 32 + nt * 16 + lm;
                    float val = acc[m][nt][i] + shift;
                    size_t idx = (size_t)(b * 128 + (p >> 5)) * 8192 + (c >> 4) * 512 +
                                 ((p >> 3) & 3) * 128 + (c & 15) * 8 + (p & 7);
                    vF[idx] = (unsigned short)f_to_bf16(val);
                }
            }
        }
    }
}

// ---------- K3: k-conv as tap-decomposed f16 MFMA GEMM, 16 waves, 4-way c-split ----------
__global__ __launch_bounds__(1024, 4) void pam_kconv_mfma(
    const unsigned short* __restrict__ xF,
    const unsigned short* __restrict__ wkF,
    const float* __restrict__ affK,
    unsigned short* __restrict__ kF) {
    __shared__ float red[3 * 4 * 64 * 8];   // 24 KiB
    int t = threadIdx.x;
    int hk = blockIdx.x, b = blockIdx.y;
    int wid = t >> 6, lane = t & 63, g = lane >> 4, lm = lane & 15;
    int dt = wid & 3, cq = wid >> 2;
    int goff = g * 8;
    f32x4 acc0 = (f32x4){0.f, 0.f, 0.f, 0.f};
    f32x4 acc1 = (f32x4){0.f, 0.f, 0.f, 0.f};
    #pragma unroll
    for (int r = 0; r < 3; r++) {
        size_t arow = ((size_t)(b * 65 + 2 * hk + r)) * 65 * 512;
        #pragma unroll
        for (int s = 0; s < 3; s++) {
            size_t aoff = arow + (size_t)(2 * lm + s) * 512 + goff;   // pixel wk=lm
            const unsigned short* pa0 = xF + aoff;
            int tap = r * 3 + s;
            const unsigned short* pb = wkF + (((size_t)(tap * 4 + dt) * 16) * 64 + lane) * 8;
            #pragma unroll
            for (int k = 0; k < 4; k++) {
                int c0 = cq * 128 + k * 32;
                f16x8 a0 = *(const f16x8*)(pa0 + c0);
                f16x8 a1 = *(const f16x8*)(pa0 + 32 * 512 + c0);   // pixel wk=lm+16
                f16x8 bf = *(const f16x8*)(pb + (size_t)(c0 >> 5) * 512);
                acc0 = __builtin_amdgcn_mfma_f32_16x16x32_f16(a0, bf, acc0, 0, 0, 0);
                acc1 = __builtin_amdgcn_mfma_f32_16x16x32_f16(a1, bf, acc1, 0, 0, 0);
            }
        }
    }
    if (cq > 0) {
        float* dst = red + (((size_t)(cq - 1) * 4 + dt) * 64 + lane) * 8;
        *(f32x4*)dst = acc0;
        *(f32x4*)(dst + 4) = acc1;
    }
    __syncthreads();
    if (cq != 0) return;
    #pragma unroll
    for (int q = 0; q < 3; q++) {
        const float* src = red + (((size_t)q * 4 + dt) * 64 + lane) * 8;
        f32x4 p0 = *(const f32x4*)src;
        f32x4 p1 = *(const f32x4*)(src + 4);
        acc0 += p0; acc1 += p1;
    }
    int d = dt * 16 + lm;
    float sc = affK[d], sh = affK[64 + d];
    int s_ = d >> 5, gF = (d >> 3) & 3, jF = d & 7;
    #pragma unroll
    for (int i = 0; i < 4; i++) {
        int m1 = hk * 32 + g * 4 + i;         // acc0 pixel
        int m2 = m1 + 16;                     // acc1 pixel
        float v0 = fmaf(acc0[i], sc, sh);
        float v1 = fmaf(acc1[i], sc, sh);
        size_t i1 = (size_t)(b * 64 + (m1 >> 4)) * 1024 + s_ * 512 + gF * 128 + (m1 & 15) * 8 + jF;
        kF[i1] = f_to_f16(v0);
        size_t i2 = (size_t)(b * 64 + (m2 >> 4)) * 1024 + s_ * 512 + gF * 128 + (m2 & 15) * 8 + jF;
        kF[i2] = f_to_f16(v1);
    }
}

// ---------- K4: flash-style MFMA attention, fp16 Q/K, 16 m-rows/block, 4 n-phases ----------
// grid (8 b, 64 mt), 512 thr = 8 waves -> 512 blocks = 2 independent blocks/CU.
__global__ __launch_bounds__(512, 4) void pam_attn(
    const unsigned short* __restrict__ qF,
    const unsigned short* __restrict__ kF,
    const unsigned short* __restrict__ vF, unsigned short* __restrict__ outsP) {
    __shared__ unsigned short Pl[16384];   // 32 KiB
    __shared__ float redM[8][16];
    __shared__ float redS[8][16];
    int t = threadIdx.x;
    int b = blockIdx.x, mt = blockIdx.y;
    int wid = t >> 6, lane = t & 63;
    int g = lane >> 4, lm = lane & 15;

    size_t kidx = (size_t)(b * 64 + mt) * 1024 + g * 128 + lm * 8;
    f16x8 kf0 = *(const f16x8*)(kF + kidx);
    f16x8 kf1 = *(const f16x8*)(kF + kidx + 512);

    float Mrun[4], rsum[4];
    #pragma unroll
    for (int i = 0; i < 4; i++) { Mrun[i] = -3e38f; rsum[i] = 0.f; }
    f32x4 oA0 = (f32x4){0.f,0.f,0.f,0.f}, oA1 = oA0, oB0 = oA0, oB1 = oA0;

    const unsigned short* qhb = qF + (size_t)(b * 256) * 1024 + g * 128 + lm * 8;
    const unsigned short* vb  = vF + (size_t)b * 1048576 + (wid * 2) * 512 + g * 128 + lm * 8;

    for (int ph = 0; ph < 4; ++ph) {
        f32x4 ev[8];
        #pragma unroll
        for (int f = 0; f < 8; f++) ev[f] = (f32x4){0.f, 0.f, 0.f, 0.f};
        int ft0 = ph * 64 + wid * 8;
        #pragma unroll
        for (int f = 0; f < 8; f++) {
            const unsigned short* qhp = qhb + (size_t)(ft0 + f) * 1024;
            f16x8 qf0 = *(const f16x8*)(qhp);
            f16x8 qf1 = *(const f16x8*)(qhp + 512);
            f32x4 e = ev[f];
            e = __builtin_amdgcn_mfma_f32_16x16x32_f16(kf0, qf0, e, 0, 0, 0);
            e = __builtin_amdgcn_mfma_f32_16x16x32_f16(kf1, qf1, e, 0, 0, 0);
            ev[f] = e;
        }
        float pm[4];
        #pragma unroll
        for (int i = 0; i < 4; i++) {
            float m_ = ev[0][i];
            #pragma unroll
            for (int f = 1; f < 8; f++) m_ = fmaxf(m_, ev[f][i]);
            #pragma unroll
            for (int off = 1; off < 16; off <<= 1) m_ = fmaxf(m_, __shfl_xor(m_, off));
            pm[i] = m_;
        }
        if (lm == 0) {
            #pragma unroll
            for (int i = 0; i < 4; i++) redM[wid][g * 4 + i] = pm[i];
        }
        __syncthreads();   // redM visible; prev-phase PV reads of Pl complete
        float rfac[4];
        #pragma unroll
        for (int i = 0; i < 4; i++) {
            float pmax = redM[0][g * 4 + i];
            #pragma unroll
            for (int w2 = 1; w2 < 8; w2++) pmax = fmaxf(pmax, redM[w2][g * 4 + i]);
            float Mn = fmaxf(Mrun[i], pmax);
            rfac[i] = __expf(Mrun[i] - Mn);
            Mrun[i] = Mn;
        }
        #pragma unroll
        for (int i = 0; i < 4; i++) {
            rsum[i] *= rfac[i];
            oA0[i] *= rfac[i]; oA1[i] *= rfac[i];
            oB0[i] *= rfac[i]; oB1[i] *= rfac[i];
        }
        #pragma unroll
        for (int f = 0; f < 8; f++) {
            int ntl = wid * 8 + f;
            int ks = ntl >> 1;
            int gF = (ntl & 1) * 2 + (lm >> 3);
            int jF = lm & 7;
            #pragma unroll
            for (int i = 0; i < 4; i++) {
                float p = __expf(ev[f][i] - Mrun[i]);
                uint32_t u = f_to_bf16(p);
                rsum[i] += bf16hi_to_f(u << 16);
                Pl[((ks * 4 + gF) * 16 + (g * 4 + i)) * 8 + jF] = (unsigned short)u;
            }
        }
        __syncthreads();   // P ready
        #pragma unroll 8
        for (int ks = 0; ks < 32; ks++) {
            bf16x8 pa = *(const bf16x8*)(Pl + ((ks * 4 + g) * 16 + lm) * 8);
            bf16x8 bvA = *(const bf16x8*)(vb + (size_t)(ph * 32 + ks) * 8192);
            bf16x8 bvB = *(const bf16x8*)(vb + (size_t)(ph * 32 + ks) * 8192 + 512);
            if (ks & 1) {
                oA1 = __builtin_amdgcn_mfma_f32_16x16x32_bf16(pa, bvA, oA1, 0, 0, 0);
                oB1 = __builtin_amdgcn_mfma_f32_16x16x32_bf16(pa, bvB, oB1, 0, 0, 0);
            } else {
                oA0 = __builtin_amdgcn_mfma_f32_16x16x32_bf16(pa, bvA, oA0, 0, 0, 0);
                oB0 = __builtin_amdgcn_mfma_f32_16x16x32_bf16(pa, bvB, oB0, 0, 0, 0);
            }
        }
    }

    #pragma unroll
    for (int i = 0; i < 4; i++) {
        float s_ = rsum[i];
        #pragma unroll
        for (int off = 1; off < 16; off <<= 1) s_ += __shfl_xor(s_, off);
        rsum[i] = s_;
    }
    __syncthreads();
    if (lm == 0) {
        #pragma unroll
        for (int i = 0; i < 4; i++) redS[wid][g * 4 + i] = rsum[i];
    }
    __syncthreads();
    f32x4 ofA = oA0 + oA1;
    f32x4 ofB = oB0 + oB1;
    int c0 = wid * 32;
    #pragma unroll
    for (int i = 0; i < 4; i++) {
        float s_ = 0.f;
        #pragma unroll
        for (int w2 = 0; w2 < 8; w2++) s_ += redS[w2][g * 4 + i];
        float sinv = 1.f / s_;
        int m = mt * 16 + g * 4 + i;
        int hk2 = m >> 5, wk2 = m & 31;
        unsigned short* op = outsP + (((size_t)(b * 33 + hk2)) * 33 + wk2) * 256;
        op[c0 + lm]      = (unsigned short)f_to_bf16(ofA[i] * sinv);
        op[c0 + 16 + lm] = (unsigned short)f_to_bf16(ofB[i] * sinv);
    }
}

// ---------- K5: transpose-conv as balanced row-pair MFMA, 2-block co-split ----------
template<int LROW, int KH, int KW>
__device__ __forceinline__ void deconv_tap(
    const unsigned short* __restrict__ wdF,
    const char* lb, int ct0, int lane, int lm, f32x4 (&acc)[2][2][2]) {
    constexpr int wop = (KW == 1) ? 0 : 1;
    constexpr int dw = (KW == 0) ? 1 : 0;
    constexpr int tap = KH * 3 + KW;
    int g = lane >> 4;
    int p0 = LROW * 33 + lm + dw;
    int p1 = p0 + 16;
    uint32_t s0 = ((uint32_t)(p0 & 7)) << 4;
    uint32_t s1 = ((uint32_t)(p1 & 7)) << 4;
    uint32_t b0a = (uint32_t)p0 * 512 + (uint32_t)g * 16;
    uint32_t b1a = (uint32_t)p1 * 512 + (uint32_t)g * 16;
    const unsigned short* a0p = wdF + ((size_t)(tap * 32 + ct0) * 8) * 512 + lane * 8;
    const unsigned short* a1p = a0p + 8 * 512;     // ct0+1
    #pragma unroll
    for (int cs = 0; cs < 8; cs++) {
        bf16x8 bv0 = *(const bf16x8*)(lb + ((b0a + (uint32_t)cs * 64) ^ s0));
        bf16x8 bv1 = *(const bf16x8*)(lb + ((b1a + (uint32_t)cs * 64) ^ s1));
        bf16x8 a0 = *(const bf16x8*)(a0p + cs * 512);
        bf16x8 a1 = *(const bf16x8*)(a1p + cs * 512);
        acc[wop][0][0] = __builtin_amdgcn_mfma_f32_16x16x32_bf16(a0, bv0, acc[wop][0][0], 0, 0, 0);
        acc[wop][0][1] = __builtin_amdgcn_mfma_f32_16x16x32_bf16(a0, bv1, acc[wop][0][1], 0, 0, 0);
        acc[wop][1][0] = __builtin_amdgcn_mfma_f32_16x16x32_bf16(a1, bv0, acc[wop][1][0], 0, 0, 0);
        acc[wop][1][1] = __builtin_amdgcn_mfma_f32_16x16x32_bf16(a1, bv1, acc[wop][1][1], 0, 0, 0);
    }
}

__device__ __forceinline__ void deconv_epi(
    const f32x4 (&acc)[2][2][2], const float* __restrict__ affD,
    const float* __restrict__ x, float* __restrict__ out,
    int b, int ho, int co0, int lm, int g) {
    #pragma unroll
    for (int mf = 0; mf < 2; mf++) {
        #pragma unroll
        for (int i = 0; i < 4; i++) {
            int co = co0 + mf * 16 + g * 4 + i;
            float sc = affD[co], sh = affD[512 + co];
            const float* xr = x + (((size_t)b * 512 + co) * 64 + ho) * 64;
            float* orow = out + (((size_t)b * 512 + co) * 64 + ho) * 64;
            #pragma unroll
            for (int nf = 0; nf < 2; nf++) {
                int wp = nf * 16 + lm;
                float2 xv = *(const float2*)(xr + 2 * wp);
                float2 st;
                st.x = fmaxf(fmaf(acc[0][mf][nf][i], sc, sh), 0.f) + xv.x;
                st.y = fmaxf(fmaf(acc[1][mf][nf][i], sc, sh), 0.f) + xv.y;
                *(float2*)(orow + 2 * wp) = st;
            }
        }
    }
}

__global__ __launch_bounds__(512, 4) void pam_deconv_mfma(
    const unsigned short* __restrict__ outsP,
    const unsigned short* __restrict__ wdF,
    const float* __restrict__ affD, const float* __restrict__ x, float* __restrict__ out) {
    __shared__ unsigned short Pb[16896];   // 2 rows x 33 px x 256 ci
    int t = threadIdx.x;
    int h0 = blockIdx.x, b = blockIdx.y, zh = blockIdx.z;   // zh = co half
    const unsigned short* src = outsP + ((size_t)(b * 33 + h0) * 33) * 256;
    for (int idx = t; idx < 2112; idx += 512) {
        uint4 v = *(const uint4*)(src + (size_t)idx * 8);
        uint32_t byte = (uint32_t)idx * 16;
        byte ^= ((byte >> 9) & 7) << 4;
        *(uint4*)((char*)Pb + byte) = v;
    }
    __syncthreads();

    int wid = t >> 6, lane = t & 63, g = lane >> 4, lm = lane & 15;
    int ct0 = (zh * 8 + wid) * 2, co0 = (zh * 8 + wid) * 32;
    const char* lb = (const char*)Pb;

    {   // even output row ho = 2*h0 : kh=1, B row h0 (LDS row 0)
        f32x4 acc[2][2][2];
        #pragma unroll
        for (int a = 0; a < 2; a++)
            #pragma unroll
            for (int m = 0; m < 2; m++)
                #pragma unroll
                for (int n = 0; n < 2; n++) acc[a][m][n] = (f32x4){0.f, 0.f, 0.f, 0.f};
        deconv_tap<0, 1, 0>(wdF, lb, ct0, lane, lm, acc);
        deconv_tap<0, 1, 1>(wdF, lb, ct0, lane, lm, acc);
        deconv_tap<0, 1, 2>(wdF, lb, ct0, lane, lm, acc);
        deconv_epi(acc, affD, x, out, b, 2 * h0, co0, lm, g);
    }
    {   // odd output row ho = 2*h0+1 : kh=2 B row h0, kh=0 B row h0+1
        f32x4 acc[2][2][2];
        #pragma unroll
        for (int a = 0; a < 2; a++)
            #pragma unroll
            for (int m = 0; m < 2; m++)
                #pragma unroll
                for (int n = 0; n < 2; n++) acc[a][m][n] = (f32x4){0.f, 0.f, 0.f, 0.f};
        deconv_tap<0, 2, 0>(wdF, lb, ct0, lane, lm, acc);
        deconv_tap<0, 2, 1>(wdF, lb, ct0, lane, lm, acc);
        deconv_tap<0, 2, 2>(wdF, lb, ct0, lane, lm, acc);
        deconv_tap<1, 0, 0>(wdF, lb, ct0, lane, lm, acc);
        deconv_tap<1, 0, 1>(wdF, lb, ct0, lane, lm, acc);
        deconv_tap<1, 0, 2>(wdF, lb, ct0, lane, lm, acc);
        deconv_epi(acc, affD, x, out, b, 2 * h0 + 1, co0, lm, g);
    }
}

// ---------- launcher ----------
extern "C" void kernel_launch(void* const* d_in, const int* in_sizes, int n_in,
                              void* d_out, int out_size, void* d_ws, size_t ws_size,
                              hipStream_t stream) {
    const float* x   = (const float*)d_in[0];
    const float* w_q = (const float*)d_in[1];
    const float* b_q = (const float*)d_in[2];
    const float* qs  = (const float*)d_in[3];
    const float* qb  = (const float*)d_in[4];
    const float* qm  = (const float*)d_in[5];
    const float* qv  = (const float*)d_in[6];
    const float* w_k = (const float*)d_in[7];
    const float* b_k = (const float*)d_in[8];
    const float* ks  = (const float*)d_in[9];
    const float* kb  = (const float*)d_in[10];
    const float* km  = (const float*)d_in[11];
    const float* kv  = (const float*)d_in[12];
    const float* w_v = (const float*)d_in[13];
    const float* b_v = (const float*)d_in[14];
    const float* w_d = (const float*)d_in[15];
    const float* ds  = (const float*)d_in[16];
    const float* db  = (const float*)d_in[17];
    const float* dm  = (const float*)d_in[18];
    const float* dv  = (const float*)d_in[19];
    float* out = (float*)d_out;

    char* wsb = (char*)d_ws;
    unsigned short* qF    = (unsigned short*)(wsb);               //  4,194,304 (f16)
    unsigned short* vF    = (unsigned short*)(wsb + 8388608);     // 16,777,216
    unsigned short* kF    = (unsigned short*)(wsb + 25165824);    //  1,048,576 (f16)
    unsigned short* wqvF  = (unsigned short*)(wsb + 26214400);    //    327,680 (f16)
    unsigned short* wkF   = (unsigned short*)(wsb + 27262976);    //    589,824 (f16)
    float*          affQ  = (float*)(wsb + 28442624);             //        512
    float*          affK  = (float*)(wsb + 28443136);             //        512
    float*          affD  = (float*)(wsb + 28443648);             //      4,096
    // X region: xF f16 live [pam_xt .. pam_kconv_mfma]; then reused:
    unsigned short* xF    = (unsigned short*)(wsb + 28447744);    // 34,611,200
    unsigned short* outsP = (unsigned short*)(wsb + 28447744);    //  4,460,544 (alias)
    unsigned short* wdF   = (unsigned short*)(wsb + 32908288);    //  2,359,296 (alias)

    hipLaunchKernelGGL(pam_prep1, dim3(1795), dim3(256), 0, stream,
                       w_k, w_q, w_v, b_q, qs, qb, qm, qv, b_k, ks, kb, km, kv,
                       ds, db, dm, dv, wkF, wqvF, affQ, affK, affD);
    hipLaunchKernelGGL(pam_xt, dim3(65, 8), dim3(256), 0, stream, x, xF);
    hipLaunchKernelGGL(pam_qv_mfma, dim3(128, 8), dim3(256), 0, stream,
                       xF, wqvF, affQ, b_v, qF, vF);
    hipLaunchKernelGGL(pam_kconv_mfma, dim3(32, 8), dim3(1024), 0, stream,
                       xF, wkF, affK, kF);
    // xF dead from here; aliased region reused for outsP / wdF.
    hipLaunchKernelGGL(pam_prep2, dim3(5697), dim3(256), 0, stream, w_d, wdF, outsP);
    hipLaunchKernelGGL(pam_attn, dim3(8, 64), dim3(512), 0, stream,
                       qF, kF, vF, outsP);
    hipLaunchKernelGGL(pam_deconv_mfma, dim3(32, 8, 2), dim3(512), 0, stream,
                       outsP, wdF, affD, x, out);
}